// Round 6
// baseline (2602.508 us; speedup 1.0000x reference)
//
#include <hip/hip_runtime.h>
#include <hip/hip_bf16.h>
#include <math.h>

// Problem constants
#define HID  1024
#define NEXP 8
#define CAP  1536
#define NTOK 4096   // B*S

// Output layout (fp32), flat in reference return order
#define DISP_OFF 0ull
#define COMB_OFF 50331648ull
#define RP_OFF   100663296ull
#define AUX_OFF  100696064ull

typedef float f32x4 __attribute__((ext_vector_type(4)));
typedef short s16x8 __attribute__((ext_vector_type(8)));
typedef unsigned short u16;

// ws layout (float units):
//   part[16][4096][8] | cnt | worklist[2048] | XH | XM | WH | WM (bf16 pairs)
#define PART_F 524288
#define CNT_F  524288
#define WL_F   524289
#define MAXFIX 2048
#define OXH_F  526400
#define OXM_F  2623552
#define OWH_F  4720704
#define OWM_F  5244992

#define TAU12 4e-3f   // rank1/rank2 prob gap -> exact recompute (order flip risk)
#define TAU23 1e-3f   // rank2/rank3 prob gap -> exact recompute (set flip risk)

// fp32 -> (bf16 hi, bf16 mid), RNE both
__device__ __forceinline__ void cvt8(const float4 v0, const float4 v1, s16x8& hi, s16x8& mi)
{
    float f[8] = {v0.x, v0.y, v0.z, v0.w, v1.x, v1.y, v1.z, v1.w};
#pragma unroll
    for (int i = 0; i < 8; ++i) {
        __hip_bfloat16 h = __float2bfloat16(f[i]);
        float fh = __bfloat162float(h);
        __hip_bfloat16 m = __float2bfloat16(f[i] - fh);
        hi[i] = (short)__builtin_bit_cast(unsigned short, h);
        mi[i] = (short)__builtin_bit_cast(unsigned short, m);
    }
}

__device__ __forceinline__ void gload16(const void* g, void* l)
{
    __builtin_amdgcn_global_load_lds(
        (const __attribute__((address_space(1))) unsigned int*)g,
        (__attribute__((address_space(3))) unsigned int*)l, 16, 0, 0);
}

// ---------------- Zero: dispatch+combine = 402.7 MB of zeros ----------------
// 2048 blocks x 256 thr x 48 f32x4 = 25,165,824 f32x4
__global__ __launch_bounds__(256) void zero_kernel(float* __restrict__ out)
{
    f32x4* p = (f32x4*)out + (size_t)blockIdx.x * 12288 + threadIdx.x;
    f32x4 z = (f32x4)0.0f;
#pragma unroll 8
    for (int i = 0; i < 48; ++i) { __builtin_nontemporal_store(z, p); p += 256; }
}

// ---------------- Prep: fp32 -> bf16 hi/mid split of x and w1 ----------------
// 2560 blocks x 256 thr = 655,360 groups of 8 (x: 524288, w1: 131072)
__global__ __launch_bounds__(256) void prep_kernel(
    const float* __restrict__ X, const float* __restrict__ W1, float* __restrict__ ws)
{
    const int g = blockIdx.x * 256 + threadIdx.x;
    if (g == 0) ((int*)(ws + CNT_F))[0] = 0;    // reset fixup counter every call
    const float* src;
    u16 *dh, *dm;
    int idx;
    if (g < 524288) { src = X;  dh = (u16*)(ws + OXH_F); dm = (u16*)(ws + OXM_F); idx = g; }
    else            { src = W1; dh = (u16*)(ws + OWH_F); dm = (u16*)(ws + OWM_F); idx = g - 524288; }
    float4 v0 = *(const float4*)(src + (size_t)idx * 8);
    float4 v1 = *(const float4*)(src + (size_t)idx * 8 + 4);
    s16x8 hi, mi;
    cvt8(v0, v1, hi, mi);
    *(s16x8*)(dh + (size_t)idx * 8) = hi;
    *(s16x8*)(dm + (size_t)idx * 8) = mi;
}

// ---------------- GEMM: split-bf16 MFMA, 2-phase pipelined ----------------
// Tile 128x128, BK=64, 4 waves 2x2, double-buffered LDS (2 x 64 KB).
// Swizzle: chunk c of row r at slot c^(r&7) (pre-swizzled gload source + swz read).
__global__ __launch_bounds__(256) void gemm_kernel(
    const float* __restrict__ B1, const float* __restrict__ W2, float* __restrict__ ws)
{
    __shared__ s16x8 L[2][4][128][8];   // [buf][Ah,Am,Bh,Bm][row][slot16B]
    const int tid = threadIdx.x, bid = blockIdx.x;

    const int n0 = (bid & 7) * 128;
    const int m0 = (bid >> 3) * 128;
    const int wave = tid >> 6, lane = tid & 63;
    const int wr = wave >> 1, wc = wave & 1;
    const int fr = lane & 15, fk = lane >> 4;

    const u16* XH = (const u16*)(ws + OXH_F);
    const u16* XM = (const u16*)(ws + OXM_F);
    const u16* WH = (const u16*)(ws + OWH_F);
    const u16* WM = (const u16*)(ws + OWM_F);

    // staging: wave w owns subtile w (0:Ah 1:Am 2:Bh 3:Bm); lane covers row sr
    // (within an 8-row group) slot sc; slot sc holds global chunk sc^sr.
    const int sr = lane >> 3, sc = lane & 7;
    const u16* sb = (wave & 2)
        ? (((wave & 1) ? WM : WH) + (size_t)(n0 + sr) * HID + ((sc ^ sr) << 3))
        : (((wave & 1) ? XM : XH) + (size_t)(m0 + sr) * HID + ((sc ^ sr) << 3));
    char* db = (char*)&L[0][wave][0][0];

    f32x4 acc[4][4];
#pragma unroll
    for (int i = 0; i < 4; ++i)
#pragma unroll
        for (int j = 0; j < 4; ++j) acc[i][j] = (f32x4)0.0f;

    // prologue: stage tile 0 into buf 0
    {
        const u16* s = sb;
#pragma unroll
        for (int i = 0; i < 16; ++i)
            gload16(s + (size_t)i * 8 * HID, db + i * 1024);
    }
    __syncthreads();    // vmcnt(0): tile 0 resident

    for (int kk = 0; kk < 16; ++kk) {
        const int b = kk & 1;
        if (kk + 1 < 16) {
            // issue next tile's staging; latency hides under this tile's MFMAs
            const u16* s = sb + (kk + 1) * 64;
            char* d = db + (b ^ 1) * 65536;
#pragma unroll
            for (int i = 0; i < 16; ++i)
                gload16(s + (size_t)i * 8 * HID, d + i * 1024);
        }

        const s16x8 (*LAh)[8] = L[b][0];
        const s16x8 (*LAm)[8] = L[b][1];
        const s16x8 (*LBh)[8] = L[b][2];
        const s16x8 (*LBm)[8] = L[b][3];
#pragma unroll
        for (int ks = 0; ks < 2; ++ks) {
            const int sl = (ks * 4 + fk) ^ (fr & 7);   // row&7 == fr&7 for all frags
            s16x8 bh[4], bm[4];
#pragma unroll
            for (int j = 0; j < 4; ++j) {
                const int rb = wc * 64 + j * 16 + fr;
                bh[j] = LBh[rb][sl];
                bm[j] = LBm[rb][sl];
            }
#pragma unroll
            for (int i = 0; i < 4; ++i) {
                const int ra = wr * 64 + i * 16 + fr;
                s16x8 ah = LAh[ra][sl];
                s16x8 am = LAm[ra][sl];
#pragma unroll
                for (int j = 0; j < 4; ++j) {
                    acc[i][j] = __builtin_amdgcn_mfma_f32_16x16x32_bf16(ah, bh[j], acc[i][j], 0, 0, 0);
                    acc[i][j] = __builtin_amdgcn_mfma_f32_16x16x32_bf16(ah, bm[j], acc[i][j], 0, 0, 0);
                    acc[i][j] = __builtin_amdgcn_mfma_f32_16x16x32_bf16(am, bh[j], acc[i][j], 0, 0, 0);
                }
            }
        }
        __syncthreads();   // drains vmcnt (next tile staged) + all reads of buf b done
    }

    // ---- epilogue: bias+relu, layer-2 partials over this wave's 64 cols ----
    // C/D: lane holds D[fk*4+r][fr] per 16x16 frag
    const int colbase = n0 + wc * 64 + fr;
#pragma unroll
    for (int j = 0; j < 4; ++j) {
        const float bj = B1[colbase + j * 16];
#pragma unroll
        for (int i = 0; i < 4; ++i)
#pragma unroll
            for (int r = 0; r < 4; ++r)
                acc[i][j][r] = fmaxf(acc[i][j][r] + bj, 0.f);
    }

    const int slice = (bid & 7) * 2 + wc;
    float* pbase = ws + ((size_t)slice * NTOK + (m0 + wr * 64 + fk * 4)) * NEXP;
#pragma unroll
    for (int e = 0; e < 8; ++e) {
        const float w20 = W2[e * HID + colbase];
        const float w21 = W2[e * HID + colbase + 16];
        const float w22 = W2[e * HID + colbase + 32];
        const float w23 = W2[e * HID + colbase + 48];
        float pe[16];
#pragma unroll
        for (int i = 0; i < 4; ++i)
#pragma unroll
            for (int r = 0; r < 4; ++r)
                pe[i * 4 + r] = acc[i][0][r] * w20 + acc[i][1][r] * w21 +
                                acc[i][2][r] * w22 + acc[i][3][r] * w23;
#pragma unroll
        for (int m = 1; m <= 8; m <<= 1)
#pragma unroll
            for (int q = 0; q < 16; ++q)
                pe[q] += __shfl_xor(pe[q], m, 64);
        if (fr == 0) {
#pragma unroll
            for (int i = 0; i < 4; ++i)
#pragma unroll
                for (int r = 0; r < 4; ++r)
                    pbase[(size_t)(i * 16 + r) * NEXP + e] = pe[i * 4 + r];
        }
    }
}

// ---------------- Router: sum partials, softmax, top-2, scatter, flag ties ----
__global__ __launch_bounds__(256) void router2_kernel(
    float* __restrict__ ws, const float* __restrict__ B2, float* __restrict__ out)
{
    const int t = blockIdx.x * 256 + threadIdx.x;
    float lg[8];
#pragma unroll
    for (int e = 0; e < 8; ++e) lg[e] = 0.f;
#pragma unroll
    for (int s = 0; s < 16; ++s) {      // fixed order -> deterministic
        const float* p = ws + ((size_t)s * NTOK + t) * NEXP;
        f32x4 v0 = *(const f32x4*)p;
        f32x4 v1 = *(const f32x4*)(p + 4);
        lg[0] += v0.x; lg[1] += v0.y; lg[2] += v0.z; lg[3] += v0.w;
        lg[4] += v1.x; lg[5] += v1.y; lg[6] += v1.z; lg[7] += v1.w;
    }
#pragma unroll
    for (int e = 0; e < 8; ++e) lg[e] += B2[e];

    float mx = lg[0];
#pragma unroll
    for (int e = 1; e < 8; ++e) mx = fmaxf(mx, lg[e]);
    float pr[8], s = 0.f;
#pragma unroll
    for (int e = 0; e < 8; ++e) { pr[e] = expf(lg[e] - mx); s += pr[e]; }
    const float inv = 1.f / s;
#pragma unroll
    for (int e = 0; e < 8; ++e) pr[e] *= inv;

    int e1 = 0; float p1 = pr[0];
#pragma unroll
    for (int e = 1; e < 8; ++e) if (pr[e] > p1) { p1 = pr[e]; e1 = e; }
    int e2 = -1; float p2 = -1.f;
#pragma unroll
    for (int e = 0; e < 8; ++e) if (e != e1 && pr[e] > p2) { p2 = pr[e]; e2 = e; }
    float p3 = -1.f;
#pragma unroll
    for (int e = 0; e < 8; ++e) if (e != e1 && e != e2 && pr[e] > p3) p3 = pr[e];

    const float invs = 1.f / (p1 + p2);
    float* rp = out + RP_OFF + (size_t)t * NEXP;
    f32x4 o0 = {pr[0], pr[1], pr[2], pr[3]};
    f32x4 o1 = {pr[4], pr[5], pr[6], pr[7]};
    *(f32x4*)rp = o0; *(f32x4*)(rp + 4) = o1;

    const size_t base = (size_t)t * NEXP;
    out[DISP_OFF + (base + e1) * CAP] = 1.0f;
    out[DISP_OFF + (base + e2) * CAP] = 1.0f;
    out[COMB_OFF + (base + e1) * CAP] = p1 * invs;
    out[COMB_OFF + (base + e2) * CAP] = p2 * invs;

    // near-tie (order-flip or set-flip risk) -> exact fp32 recompute
    if ((p1 - p2 < TAU12) || (p2 - p3 < TAU23)) {
        int* cnt = (int*)(ws + CNT_F);
        int idx = atomicAdd(cnt, 1);
        if (idx < MAXFIX)
            ((unsigned*)(ws + WL_F))[idx] = ((unsigned)t << 8) | ((unsigned)e1 << 4) | (unsigned)e2;
    }
}

// ---------------- Fixup: exact fp32 (ascending-k) recompute of flagged tokens ----
__global__ __launch_bounds__(256) void fixup_kernel(
    const float* __restrict__ X,  const float* __restrict__ W1,
    const float* __restrict__ B1, const float* __restrict__ W2,
    const float* __restrict__ B2, float* __restrict__ ws, float* __restrict__ out)
{
    __shared__ float xs[HID];
    __shared__ float hs[HID];
    __shared__ float lgs[NEXP];
    const int tid = threadIdx.x;
    const int cnt0 = ((const int*)(ws + CNT_F))[0];
    const int cnt = cnt0 < MAXFIX ? cnt0 : MAXFIX;
    const unsigned* wl = (const unsigned*)(ws + WL_F);

    for (int idx = blockIdx.x; idx < cnt; idx += 64) {
        const unsigned ent = wl[idx];
        const int t = (int)(ent >> 8), oe1 = (ent >> 4) & 15, oe2 = ent & 15;
        for (int i = tid; i < HID; i += 256) xs[i] = X[(size_t)t * HID + i];
        __syncthreads();
        const float* w0p = W1 + (size_t)(tid * 4 + 0) * HID;
        const float* w1p = W1 + (size_t)(tid * 4 + 1) * HID;
        const float* w2p = W1 + (size_t)(tid * 4 + 2) * HID;
        const float* w3p = W1 + (size_t)(tid * 4 + 3) * HID;
        float a0 = 0.f, a1 = 0.f, a2 = 0.f, a3 = 0.f;
#pragma unroll 4
        for (int k = 0; k < HID; ++k) {
            const float xk = xs[k];
            a0 = fmaf(xk, w0p[k], a0);
            a1 = fmaf(xk, w1p[k], a1);
            a2 = fmaf(xk, w2p[k], a2);
            a3 = fmaf(xk, w3p[k], a3);
        }
        hs[tid * 4 + 0] = fmaxf(a0 + B1[tid * 4 + 0], 0.f);
        hs[tid * 4 + 1] = fmaxf(a1 + B1[tid * 4 + 1], 0.f);
        hs[tid * 4 + 2] = fmaxf(a2 + B1[tid * 4 + 2], 0.f);
        hs[tid * 4 + 3] = fmaxf(a3 + B1[tid * 4 + 3], 0.f);
        __syncthreads();
        if (tid < 8) {
            float sl = 0.f;
            const float* wp = W2 + (size_t)tid * HID;
            for (int k = 0; k < HID; ++k) sl = fmaf(hs[k], wp[k], sl);
            lgs[tid] = sl + B2[tid];
        }
        __syncthreads();
        if (tid == 0) {
            float mx = lgs[0];
#pragma unroll
            for (int e = 1; e < 8; ++e) mx = fmaxf(mx, lgs[e]);
            float pr[8], sv = 0.f;
#pragma unroll
            for (int e = 0; e < 8; ++e) { pr[e] = expf(lgs[e] - mx); sv += pr[e]; }
            const float inv = 1.f / sv;
#pragma unroll
            for (int e = 0; e < 8; ++e) pr[e] *= inv;
            int e1 = 0; float p1v = pr[0];
#pragma unroll
            for (int e = 1; e < 8; ++e) if (pr[e] > p1v) { p1v = pr[e]; e1 = e; }
            int e2 = -1; float p2v = -1.f;
#pragma unroll
            for (int e = 0; e < 8; ++e) if (e != e1 && pr[e] > p2v) { p2v = pr[e]; e2 = e; }
            const float invs = 1.f / (p1v + p2v);
            const size_t base = (size_t)t * NEXP;
            out[DISP_OFF + (base + oe1) * CAP] = 0.f;
            out[DISP_OFF + (base + oe2) * CAP] = 0.f;
            out[COMB_OFF + (base + oe1) * CAP] = 0.f;
            out[COMB_OFF + (base + oe2) * CAP] = 0.f;
            out[DISP_OFF + (base + e1) * CAP] = 1.0f;
            out[DISP_OFF + (base + e2) * CAP] = 1.0f;
            out[COMB_OFF + (base + e1) * CAP] = p1v * invs;
            out[COMB_OFF + (base + e2) * CAP] = p2v * invs;
            float* rp = out + RP_OFF + base;
#pragma unroll
            for (int e = 0; e < 8; ++e) rp[e] = pr[e];
        }
        __syncthreads();
    }
}

// ---------------- Aux loss ----------------
__global__ __launch_bounds__(256) void aux_kernel(float* __restrict__ out)
{
    __shared__ float sm[NEXP][257];
    const int tid = threadIdx.x;
    float s[NEXP];
#pragma unroll
    for (int e = 0; e < 8; ++e) s[e] = 0.f;
    const float* rp = out + RP_OFF;
    for (int t = tid; t < NTOK; t += 256) {
        f32x4 v0 = *(const f32x4*)&rp[(size_t)t * NEXP];
        f32x4 v1 = *(const f32x4*)&rp[(size_t)t * NEXP + 4];
        s[0] += v0.x; s[1] += v0.y; s[2] += v0.z; s[3] += v0.w;
        s[4] += v1.x; s[5] += v1.y; s[6] += v1.z; s[7] += v1.w;
    }
#pragma unroll
    for (int e = 0; e < 8; ++e) sm[e][tid] = s[e];
    __syncthreads();
    for (int st = 128; st > 0; st >>= 1) {
        if (tid < st) {
#pragma unroll
            for (int e = 0; e < 8; ++e) sm[e][tid] += sm[e][tid + st];
        }
        __syncthreads();
    }
    if (tid == 0) {
        float loss = 0.f;
#pragma unroll
        for (int e = 0; e < 8; ++e) {
            float m = sm[e][0] * (1.0f / NTOK);
            loss += m * logf(m * (float)NEXP + 1e-9f);
        }
        out[AUX_OFF] = loss;
    }
}

extern "C" void kernel_launch(void* const* d_in, const int* in_sizes, int n_in,
                              void* d_out, int out_size, void* d_ws, size_t ws_size,
                              hipStream_t stream)
{
    const float* x  = (const float*)d_in[0];
    const float* w1 = (const float*)d_in[1];
    const float* b1 = (const float*)d_in[2];
    const float* w2 = (const float*)d_in[3];
    const float* b2 = (const float*)d_in[4];
    float* out = (float*)d_out;
    float* ws  = (float*)d_ws;     // ~23 MB used

    // Split kernels for per-phase rocprof attribution (was fused in R4/R5).
    zero_kernel<<<2048, 256, 0, stream>>>(out);
    prep_kernel<<<2560, 256, 0, stream>>>(x, w1, ws);
    gemm_kernel<<<256, 256, 0, stream>>>(b1, w2, ws);
    router2_kernel<<<16, 256, 0, stream>>>(ws, b2, out);
    fixup_kernel<<<64, 256, 0, stream>>>(x, w1, b1, w2, b2, ws, out);
    aux_kernel<<<1, 256, 0, stream>>>(out);
}

// Round 7
// 475.213 us; speedup vs baseline: 5.4765x; 5.4765x over previous
//
#include <hip/hip_runtime.h>
#include <hip/hip_bf16.h>
#include <math.h>

// Problem constants
#define HID  1024
#define NEXP 8
#define CAP  1536
#define NTOK 4096   // B*S

// Output layout (fp32), flat in reference return order
#define DISP_OFF 0ull
#define COMB_OFF 50331648ull
#define RP_OFF   100663296ull
#define AUX_OFF  100696064ull

typedef float f32x4 __attribute__((ext_vector_type(4)));
typedef short s16x8 __attribute__((ext_vector_type(8)));
typedef unsigned short u16;

// ws layout (float units): part[16][4096][8] | XH | XM | WH | WM (bf16 pairs)
#define PART_F 524288
#define OXH_F  526400
#define OXM_F  2623552
#define OWH_F  4720704
#define OWM_F  5244992

// fp32 -> (bf16 hi, bf16 mid), RNE both
__device__ __forceinline__ void cvt8(const float4 v0, const float4 v1, s16x8& hi, s16x8& mi)
{
    float f[8] = {v0.x, v0.y, v0.z, v0.w, v1.x, v1.y, v1.z, v1.w};
#pragma unroll
    for (int i = 0; i < 8; ++i) {
        __hip_bfloat16 h = __float2bfloat16(f[i]);
        float fh = __bfloat162float(h);
        __hip_bfloat16 m = __float2bfloat16(f[i] - fh);
        hi[i] = (short)__builtin_bit_cast(unsigned short, h);
        mi[i] = (short)__builtin_bit_cast(unsigned short, m);
    }
}

__device__ __forceinline__ void gload16(const void* g, void* l)
{
    __builtin_amdgcn_global_load_lds(
        (const __attribute__((address_space(1))) unsigned int*)g,
        (__attribute__((address_space(3))) unsigned int*)l, 16, 0, 0);
}

// ---------------- Zero: dispatch+combine = 402.7 MB of zeros ----------------
__global__ __launch_bounds__(256) void zero_kernel(float* __restrict__ out)
{
    f32x4* p = (f32x4*)out + (size_t)blockIdx.x * 12288 + threadIdx.x;
    f32x4 z = (f32x4)0.0f;
#pragma unroll 8
    for (int i = 0; i < 48; ++i) { __builtin_nontemporal_store(z, p); p += 256; }
}

// ---------------- Prep: fp32 -> bf16 hi/mid split of x and w1 ----------------
__global__ __launch_bounds__(256) void prep_kernel(
    const float* __restrict__ X, const float* __restrict__ W1, float* __restrict__ ws)
{
    const int g = blockIdx.x * 256 + threadIdx.x;
    const float* src;
    u16 *dh, *dm;
    int idx;
    if (g < 524288) { src = X;  dh = (u16*)(ws + OXH_F); dm = (u16*)(ws + OXM_F); idx = g; }
    else            { src = W1; dh = (u16*)(ws + OWH_F); dm = (u16*)(ws + OWM_F); idx = g - 524288; }
    float4 v0 = *(const float4*)(src + (size_t)idx * 8);
    float4 v1 = *(const float4*)(src + (size_t)idx * 8 + 4);
    s16x8 hi, mi;
    cvt8(v0, v1, hi, mi);
    *(s16x8*)(dh + (size_t)idx * 8) = hi;
    *(s16x8*)(dm + (size_t)idx * 8) = mi;
}

// ---------------- GEMM: split-bf16 MFMA, 2-phase pipelined ----------------
// Tile 128x128, BK=64, 4 waves 2x2, double-buffered LDS (2 x 64 KB).
// Swizzle: chunk c of row r at slot c^(r&7) (pre-swizzled gload source + swz read).
__global__ __launch_bounds__(256) void gemm_kernel(
    const float* __restrict__ B1, const float* __restrict__ W2, float* __restrict__ ws)
{
    __shared__ s16x8 L[2][4][128][8];   // [buf][Ah,Am,Bh,Bm][row][slot16B]
    const int tid = threadIdx.x, bid = blockIdx.x;

    const int n0 = (bid & 7) * 128;
    const int m0 = (bid >> 3) * 128;
    const int wave = tid >> 6, lane = tid & 63;
    const int wr = wave >> 1, wc = wave & 1;
    const int fr = lane & 15, fk = lane >> 4;

    const u16* XH = (const u16*)(ws + OXH_F);
    const u16* XM = (const u16*)(ws + OXM_F);
    const u16* WH = (const u16*)(ws + OWH_F);
    const u16* WM = (const u16*)(ws + OWM_F);

    // staging: wave w owns subtile w (0:Ah 1:Am 2:Bh 3:Bm); lane covers row sr
    // (within an 8-row group) slot sc; slot sc holds global chunk sc^sr.
    const int sr = lane >> 3, sc = lane & 7;
    const u16* sb = (wave & 2)
        ? (((wave & 1) ? WM : WH) + (size_t)(n0 + sr) * HID + ((sc ^ sr) << 3))
        : (((wave & 1) ? XM : XH) + (size_t)(m0 + sr) * HID + ((sc ^ sr) << 3));
    char* db = (char*)&L[0][wave][0][0];

    f32x4 acc[4][4];
#pragma unroll
    for (int i = 0; i < 4; ++i)
#pragma unroll
        for (int j = 0; j < 4; ++j) acc[i][j] = (f32x4)0.0f;

    // prologue: stage tile 0 into buf 0
    {
        const u16* s = sb;
#pragma unroll
        for (int i = 0; i < 16; ++i)
            gload16(s + (size_t)i * 8 * HID, db + i * 1024);
    }
    __syncthreads();    // tile 0 resident

    for (int kk = 0; kk < 16; ++kk) {
        const int b = kk & 1;
        if (kk + 1 < 16) {
            // issue next tile's staging; latency hides under this tile's MFMAs
            const u16* s = sb + (kk + 1) * 64;
            char* d = db + (b ^ 1) * 65536;
#pragma unroll
            for (int i = 0; i < 16; ++i)
                gload16(s + (size_t)i * 8 * HID, d + i * 1024);
        }

        const s16x8 (*LAh)[8] = L[b][0];
        const s16x8 (*LAm)[8] = L[b][1];
        const s16x8 (*LBh)[8] = L[b][2];
        const s16x8 (*LBm)[8] = L[b][3];
#pragma unroll
        for (int ks = 0; ks < 2; ++ks) {
            const int sl = (ks * 4 + fk) ^ (fr & 7);   // row&7 == fr&7 for all frags
            s16x8 bh[4], bm[4];
#pragma unroll
            for (int j = 0; j < 4; ++j) {
                const int rb = wc * 64 + j * 16 + fr;
                bh[j] = LBh[rb][sl];
                bm[j] = LBm[rb][sl];
            }
#pragma unroll
            for (int i = 0; i < 4; ++i) {
                const int ra = wr * 64 + i * 16 + fr;
                s16x8 ah = LAh[ra][sl];
                s16x8 am = LAm[ra][sl];
#pragma unroll
                for (int j = 0; j < 4; ++j) {
                    acc[i][j] = __builtin_amdgcn_mfma_f32_16x16x32_bf16(ah, bh[j], acc[i][j], 0, 0, 0);
                    acc[i][j] = __builtin_amdgcn_mfma_f32_16x16x32_bf16(ah, bm[j], acc[i][j], 0, 0, 0);
                    acc[i][j] = __builtin_amdgcn_mfma_f32_16x16x32_bf16(am, bh[j], acc[i][j], 0, 0, 0);
                }
            }
        }
        __syncthreads();   // next tile staged + all reads of buf b done
    }

    // ---- epilogue: bias+relu, layer-2 partials over this wave's 64 cols ----
    // C/D: lane holds D[fk*4+r][fr] per 16x16 frag
    const int colbase = n0 + wc * 64 + fr;
#pragma unroll
    for (int j = 0; j < 4; ++j) {
        const float bj = B1[colbase + j * 16];
#pragma unroll
        for (int i = 0; i < 4; ++i)
#pragma unroll
            for (int r = 0; r < 4; ++r)
                acc[i][j][r] = fmaxf(acc[i][j][r] + bj, 0.f);
    }

    const int slice = (bid & 7) * 2 + wc;
    float* pbase = ws + ((size_t)slice * NTOK + (m0 + wr * 64 + fk * 4)) * NEXP;
#pragma unroll
    for (int e = 0; e < 8; ++e) {
        const float w20 = W2[e * HID + colbase];
        const float w21 = W2[e * HID + colbase + 16];
        const float w22 = W2[e * HID + colbase + 32];
        const float w23 = W2[e * HID + colbase + 48];
        float pe[16];
#pragma unroll
        for (int i = 0; i < 4; ++i)
#pragma unroll
            for (int r = 0; r < 4; ++r)
                pe[i * 4 + r] = acc[i][0][r] * w20 + acc[i][1][r] * w21 +
                                acc[i][2][r] * w22 + acc[i][3][r] * w23;
#pragma unroll
        for (int m = 1; m <= 8; m <<= 1)
#pragma unroll
            for (int q = 0; q < 16; ++q)
                pe[q] += __shfl_xor(pe[q], m, 64);
        if (fr == 0) {
#pragma unroll
            for (int i = 0; i < 4; ++i)
#pragma unroll
                for (int r = 0; r < 4; ++r)
                    pbase[(size_t)(i * 16 + r) * NEXP + e] = pe[i * 4 + r];
        }
    }
}

// ---------------- Router: sum partials, softmax, top-2, scatter ----------------
__global__ __launch_bounds__(256) void router2_kernel(
    const float* __restrict__ ws, const float* __restrict__ B2, float* __restrict__ out)
{
    const int t = blockIdx.x * 256 + threadIdx.x;
    float lg[8];
#pragma unroll
    for (int e = 0; e < 8; ++e) lg[e] = 0.f;
#pragma unroll
    for (int s = 0; s < 16; ++s) {      // fixed order -> deterministic
        const float* p = ws + ((size_t)s * NTOK + t) * NEXP;
        f32x4 v0 = *(const f32x4*)p;
        f32x4 v1 = *(const f32x4*)(p + 4);
        lg[0] += v0.x; lg[1] += v0.y; lg[2] += v0.z; lg[3] += v0.w;
        lg[4] += v1.x; lg[5] += v1.y; lg[6] += v1.z; lg[7] += v1.w;
    }
#pragma unroll
    for (int e = 0; e < 8; ++e) lg[e] += B2[e];

    float mx = lg[0];
#pragma unroll
    for (int e = 1; e < 8; ++e) mx = fmaxf(mx, lg[e]);
    float pr[8], s = 0.f;
#pragma unroll
    for (int e = 0; e < 8; ++e) { pr[e] = expf(lg[e] - mx); s += pr[e]; }
    const float inv = 1.f / s;
#pragma unroll
    for (int e = 0; e < 8; ++e) pr[e] *= inv;

    // top-2 (strict > : lowest index wins exact ties, matching lax.top_k)
    int e1 = 0; float p1 = pr[0];
#pragma unroll
    for (int e = 1; e < 8; ++e) if (pr[e] > p1) { p1 = pr[e]; e1 = e; }
    int e2 = -1; float p2 = -1.f;
#pragma unroll
    for (int e = 0; e < 8; ++e) if (e != e1 && pr[e] > p2) { p2 = pr[e]; e2 = e; }

    const float invs = 1.f / (p1 + p2);
    float* rp = out + RP_OFF + (size_t)t * NEXP;
    f32x4 o0 = {pr[0], pr[1], pr[2], pr[3]};
    f32x4 o1 = {pr[4], pr[5], pr[6], pr[7]};
    *(f32x4*)rp = o0; *(f32x4*)(rp + 4) = o1;

    const size_t base = (size_t)t * NEXP;
    out[DISP_OFF + (base + e1) * CAP] = 1.0f;
    out[DISP_OFF + (base + e2) * CAP] = 1.0f;
    out[COMB_OFF + (base + e1) * CAP] = p1 * invs;
    out[COMB_OFF + (base + e2) * CAP] = p2 * invs;
}

// ---------------- Aux loss ----------------
__global__ __launch_bounds__(256) void aux_kernel(float* __restrict__ out)
{
    __shared__ float sm[NEXP][257];
    const int tid = threadIdx.x;
    float s[NEXP];
#pragma unroll
    for (int e = 0; e < 8; ++e) s[e] = 0.f;
    const float* rp = out + RP_OFF;
    for (int t = tid; t < NTOK; t += 256) {
        f32x4 v0 = *(const f32x4*)&rp[(size_t)t * NEXP];
        f32x4 v1 = *(const f32x4*)&rp[(size_t)t * NEXP + 4];
        s[0] += v0.x; s[1] += v0.y; s[2] += v0.z; s[3] += v0.w;
        s[4] += v1.x; s[5] += v1.y; s[6] += v1.z; s[7] += v1.w;
    }
#pragma unroll
    for (int e = 0; e < 8; ++e) sm[e][tid] = s[e];
    __syncthreads();
    for (int st = 128; st > 0; st >>= 1) {
        if (tid < st) {
#pragma unroll
            for (int e = 0; e < 8; ++e) sm[e][tid] += sm[e][tid + st];
        }
        __syncthreads();
    }
    if (tid == 0) {
        float loss = 0.f;
#pragma unroll
        for (int e = 0; e < 8; ++e) {
            float m = sm[e][0] * (1.0f / NTOK);
            loss += m * logf(m * (float)NEXP + 1e-9f);
        }
        out[AUX_OFF] = loss;
    }
}

extern "C" void kernel_launch(void* const* d_in, const int* in_sizes, int n_in,
                              void* d_out, int out_size, void* d_ws, size_t ws_size,
                              hipStream_t stream)
{
    const float* x  = (const float*)d_in[0];
    const float* w1 = (const float*)d_in[1];
    const float* b1 = (const float*)d_in[2];
    const float* w2 = (const float*)d_in[3];
    const float* b2 = (const float*)d_in[4];
    float* out = (float*)d_out;
    float* ws  = (float*)d_ws;     // ~23 MB used

    // Fixup machinery removed: absmax (2^-9, one near-tie order flip) was
    // invariant under all recompute strategies and passes the harness check.
    zero_kernel<<<2048, 256, 0, stream>>>(out);
    prep_kernel<<<2560, 256, 0, stream>>>(x, w1, ws);
    gemm_kernel<<<256, 256, 0, stream>>>(b1, w2, ws);
    router2_kernel<<<16, 256, 0, stream>>>(ws, b2, out);
    aux_kernel<<<1, 256, 0, stream>>>(out);
}

// Round 8
// 442.745 us; speedup vs baseline: 5.8781x; 1.0733x over previous
//
#include <hip/hip_runtime.h>
#include <hip/hip_bf16.h>
#include <math.h>

// Problem constants
#define HID  1024
#define NEXP 8
#define CAP  1536
#define NTOK 4096   // B*S

// Output layout (fp32), flat in reference return order
#define DISP_OFF 0ull
#define COMB_OFF 50331648ull
#define RP_OFF   100663296ull
#define AUX_OFF  100696064ull

typedef float f32x4 __attribute__((ext_vector_type(4)));
typedef short s16x8 __attribute__((ext_vector_type(8)));
typedef unsigned short u16;

// ws layout (float units): part[16][4096][8] | XH | XM | WH | WM (bf16 pairs)
#define PART_F 524288
#define OXH_F  526400
#define OXM_F  2623552
#define OWH_F  4720704
#define OWM_F  5244992

// fp32 -> (bf16 hi, bf16 mid), RNE both
__device__ __forceinline__ void cvt8(const float4 v0, const float4 v1, s16x8& hi, s16x8& mi)
{
    float f[8] = {v0.x, v0.y, v0.z, v0.w, v1.x, v1.y, v1.z, v1.w};
#pragma unroll
    for (int i = 0; i < 8; ++i) {
        __hip_bfloat16 h = __float2bfloat16(f[i]);
        float fh = __bfloat162float(h);
        __hip_bfloat16 m = __float2bfloat16(f[i] - fh);
        hi[i] = (short)__builtin_bit_cast(unsigned short, h);
        mi[i] = (short)__builtin_bit_cast(unsigned short, m);
    }
}

__device__ __forceinline__ void gload16(const void* g, void* l)
{
    __builtin_amdgcn_global_load_lds(
        (const __attribute__((address_space(1))) unsigned int*)g,
        (__attribute__((address_space(3))) unsigned int*)l, 16, 0, 0);
}

// ---------------- Prep: fp32 -> bf16 hi/mid split of x and w1 ----------------
__global__ __launch_bounds__(256) void prep_kernel(
    const float* __restrict__ X, const float* __restrict__ W1, float* __restrict__ ws)
{
    const int g = blockIdx.x * 256 + threadIdx.x;
    const float* src;
    u16 *dh, *dm;
    int idx;
    if (g < 524288) { src = X;  dh = (u16*)(ws + OXH_F); dm = (u16*)(ws + OXM_F); idx = g; }
    else            { src = W1; dh = (u16*)(ws + OWH_F); dm = (u16*)(ws + OWM_F); idx = g - 524288; }
    float4 v0 = *(const float4*)(src + (size_t)idx * 8);
    float4 v1 = *(const float4*)(src + (size_t)idx * 8 + 4);
    s16x8 hi, mi;
    cvt8(v0, v1, hi, mi);
    *(s16x8*)(dh + (size_t)idx * 8) = hi;
    *(s16x8*)(dm + (size_t)idx * 8) = mi;
}

// ---------------- Fused: GEMM (bid<256) + 402.7 MB zero-fill (bid>=256) --------
// GEMM: tile 128x128, BK=32, 4 waves 2x2, double-buffered 64 KB LDS ->
// 1 gemm + 1 zero block co-resident per CU (128 KB LDS, 8 waves): the HBM-bound
// zero stream overlaps the MFMA/DS-bound GEMM. K accumulation order is bitwise
// identical to the BK=64 version (same sequential K=32 chunks, same 3 passes).
// Swizzle: 16B chunk c of row r lives at slot c^(r&3); gload source pre-swizzled.
__global__ void fused_kernel(
    const float* __restrict__ B1, const float* __restrict__ W2,
    float* __restrict__ ws, float* __restrict__ out)
{
    __shared__ s16x8 L[2][4][128][4];   // [buf][Ah,Am,Bh,Bm][row][slot16B] = 64 KB
    const int tid = threadIdx.x, bid = blockIdx.x;

    if (bid >= 256) {
        // ---- zero role: 256 blocks x 256 thr x 384 f32x4 = 402.7 MB ----
        const int zid = bid - 256;
        f32x4* p = (f32x4*)out + (size_t)zid * 98304 + tid;
        f32x4 z = (f32x4)0.0f;
#pragma unroll 8
        for (int i = 0; i < 384; ++i) { __builtin_nontemporal_store(z, p); p += 256; }
        return;
    }

    // ---- GEMM role ----
    const int n0 = (bid & 7) * 128;
    const int m0 = (bid >> 3) * 128;
    const int wave = tid >> 6, lane = tid & 63;
    const int wr = wave >> 1, wc = wave & 1;
    const int fr = lane & 15, fk = lane >> 4;

    const u16* XH = (const u16*)(ws + OXH_F);
    const u16* XM = (const u16*)(ws + OXM_F);
    const u16* WH = (const u16*)(ws + OWH_F);
    const u16* WM = (const u16*)(ws + OWM_F);

    // staging: wave w owns subtile w (0:Ah 1:Am 2:Bh 3:Bm).
    // iter i, lane l covers LDS row i*16 + (l>>2), slot l&3; that slot holds
    // global chunk (l&3)^(row&3); row&3 == (l>>2)&3 since 16 = 0 mod 4.
    const int sr4 = lane >> 2;                 // row within a 16-row group
    const int cg  = (lane & 3) ^ (sr4 & 3);    // global 16B chunk for this slot
    const u16* sb = (wave & 2)
        ? (((wave & 1) ? WM : WH) + (size_t)(n0 + sr4) * HID + cg * 8)
        : (((wave & 1) ? XM : XH) + (size_t)(m0 + sr4) * HID + cg * 8);
    char* db = (char*)&L[0][wave][0][0];

    f32x4 acc[4][4];
#pragma unroll
    for (int i = 0; i < 4; ++i)
#pragma unroll
        for (int j = 0; j < 4; ++j) acc[i][j] = (f32x4)0.0f;

    // prologue: stage tile 0 into buf 0 (8 KB/subtile = 8 gload16)
#pragma unroll
    for (int i = 0; i < 8; ++i)
        gload16(sb + (size_t)i * 16 * HID, db + i * 1024);
    __syncthreads();    // tile 0 resident

    for (int kk = 0; kk < 32; ++kk) {
        const int b = kk & 1;
        if (kk + 1 < 32) {
            // issue next tile's staging; latency hides under this tile's MFMAs
            const u16* s = sb + (kk + 1) * 32;
            char* d = db + (b ^ 1) * 32768;
#pragma unroll
            for (int i = 0; i < 8; ++i)
                gload16(s + (size_t)i * 16 * HID, d + i * 1024);
        }

        const s16x8 (*LAh)[4] = L[b][0];
        const s16x8 (*LAm)[4] = L[b][1];
        const s16x8 (*LBh)[4] = L[b][2];
        const s16x8 (*LBm)[4] = L[b][3];
        const int sl = fk ^ (fr & 3);          // row&3 == fr&3 for all frag rows
        s16x8 bh[4], bm[4];
#pragma unroll
        for (int j = 0; j < 4; ++j) {
            const int rb = wc * 64 + j * 16 + fr;
            bh[j] = LBh[rb][sl];
            bm[j] = LBm[rb][sl];
        }
#pragma unroll
        for (int i = 0; i < 4; ++i) {
            const int ra = wr * 64 + i * 16 + fr;
            s16x8 ah = LAh[ra][sl];
            s16x8 am = LAm[ra][sl];
#pragma unroll
            for (int j = 0; j < 4; ++j) {
                acc[i][j] = __builtin_amdgcn_mfma_f32_16x16x32_bf16(ah, bh[j], acc[i][j], 0, 0, 0);
                acc[i][j] = __builtin_amdgcn_mfma_f32_16x16x32_bf16(ah, bm[j], acc[i][j], 0, 0, 0);
                acc[i][j] = __builtin_amdgcn_mfma_f32_16x16x32_bf16(am, bh[j], acc[i][j], 0, 0, 0);
            }
        }
        __syncthreads();   // next tile staged + all reads of buf b done
    }

    // ---- epilogue: bias+relu, layer-2 partials over this wave's 64 cols ----
    // C/D: lane holds D[fk*4+r][fr] per 16x16 frag
    const int colbase = n0 + wc * 64 + fr;
#pragma unroll
    for (int j = 0; j < 4; ++j) {
        const float bj = B1[colbase + j * 16];
#pragma unroll
        for (int i = 0; i < 4; ++i)
#pragma unroll
            for (int r = 0; r < 4; ++r)
                acc[i][j][r] = fmaxf(acc[i][j][r] + bj, 0.f);
    }

    const int slice = (bid & 7) * 2 + wc;
    float* pbase = ws + ((size_t)slice * NTOK + (m0 + wr * 64 + fk * 4)) * NEXP;
#pragma unroll
    for (int e = 0; e < 8; ++e) {
        const float w20 = W2[e * HID + colbase];
        const float w21 = W2[e * HID + colbase + 16];
        const float w22 = W2[e * HID + colbase + 32];
        const float w23 = W2[e * HID + colbase + 48];
        float pe[16];
#pragma unroll
        for (int i = 0; i < 4; ++i)
#pragma unroll
            for (int r = 0; r < 4; ++r)
                pe[i * 4 + r] = acc[i][0][r] * w20 + acc[i][1][r] * w21 +
                                acc[i][2][r] * w22 + acc[i][3][r] * w23;
#pragma unroll
        for (int m = 1; m <= 8; m <<= 1)
#pragma unroll
            for (int q = 0; q < 16; ++q)
                pe[q] += __shfl_xor(pe[q], m, 64);
        if (fr == 0) {
#pragma unroll
            for (int i = 0; i < 4; ++i)
#pragma unroll
                for (int r = 0; r < 4; ++r)
                    pbase[(size_t)(i * 16 + r) * NEXP + e] = pe[i * 4 + r];
        }
    }
}

// ---------------- Router: sum partials, softmax, top-2, scatter ----------------
__global__ __launch_bounds__(256) void router2_kernel(
    const float* __restrict__ ws, const float* __restrict__ B2, float* __restrict__ out)
{
    const int t = blockIdx.x * 256 + threadIdx.x;
    float lg[8];
#pragma unroll
    for (int e = 0; e < 8; ++e) lg[e] = 0.f;
#pragma unroll
    for (int s = 0; s < 16; ++s) {      // fixed order -> deterministic
        const float* p = ws + ((size_t)s * NTOK + t) * NEXP;
        f32x4 v0 = *(const f32x4*)p;
        f32x4 v1 = *(const f32x4*)(p + 4);
        lg[0] += v0.x; lg[1] += v0.y; lg[2] += v0.z; lg[3] += v0.w;
        lg[4] += v1.x; lg[5] += v1.y; lg[6] += v1.z; lg[7] += v1.w;
    }
#pragma unroll
    for (int e = 0; e < 8; ++e) lg[e] += B2[e];

    float mx = lg[0];
#pragma unroll
    for (int e = 1; e < 8; ++e) mx = fmaxf(mx, lg[e]);
    float pr[8], s = 0.f;
#pragma unroll
    for (int e = 0; e < 8; ++e) { pr[e] = expf(lg[e] - mx); s += pr[e]; }
    const float inv = 1.f / s;
#pragma unroll
    for (int e = 0; e < 8; ++e) pr[e] *= inv;

    // top-2 (strict > : lowest index wins exact ties, matching lax.top_k)
    int e1 = 0; float p1 = pr[0];
#pragma unroll
    for (int e = 1; e < 8; ++e) if (pr[e] > p1) { p1 = pr[e]; e1 = e; }
    int e2 = -1; float p2 = -1.f;
#pragma unroll
    for (int e = 0; e < 8; ++e) if (e != e1 && pr[e] > p2) { p2 = pr[e]; e2 = e; }

    const float invs = 1.f / (p1 + p2);
    float* rp = out + RP_OFF + (size_t)t * NEXP;
    f32x4 o0 = {pr[0], pr[1], pr[2], pr[3]};
    f32x4 o1 = {pr[4], pr[5], pr[6], pr[7]};
    *(f32x4*)rp = o0; *(f32x4*)(rp + 4) = o1;

    const size_t base = (size_t)t * NEXP;
    out[DISP_OFF + (base + e1) * CAP] = 1.0f;
    out[DISP_OFF + (base + e2) * CAP] = 1.0f;
    out[COMB_OFF + (base + e1) * CAP] = p1 * invs;
    out[COMB_OFF + (base + e2) * CAP] = p2 * invs;
}

// ---------------- Aux loss ----------------
__global__ __launch_bounds__(256) void aux_kernel(float* __restrict__ out)
{
    __shared__ float sm[NEXP][257];
    const int tid = threadIdx.x;
    float s[NEXP];
#pragma unroll
    for (int e = 0; e < 8; ++e) s[e] = 0.f;
    const float* rp = out + RP_OFF;
    for (int t = tid; t < NTOK; t += 256) {
        f32x4 v0 = *(const f32x4*)&rp[(size_t)t * NEXP];
        f32x4 v1 = *(const f32x4*)&rp[(size_t)t * NEXP + 4];
        s[0] += v0.x; s[1] += v0.y; s[2] += v0.z; s[3] += v0.w;
        s[4] += v1.x; s[5] += v1.y; s[6] += v1.z; s[7] += v1.w;
    }
#pragma unroll
    for (int e = 0; e < 8; ++e) sm[e][tid] = s[e];
    __syncthreads();
    for (int st = 128; st > 0; st >>= 1) {
        if (tid < st) {
#pragma unroll
            for (int e = 0; e < 8; ++e) sm[e][tid] += sm[e][tid + st];
        }
        __syncthreads();
    }
    if (tid == 0) {
        float loss = 0.f;
#pragma unroll
        for (int e = 0; e < 8; ++e) {
            float m = sm[e][0] * (1.0f / NTOK);
            loss += m * logf(m * (float)NEXP + 1e-9f);
        }
        out[AUX_OFF] = loss;
    }
}

extern "C" void kernel_launch(void* const* d_in, const int* in_sizes, int n_in,
                              void* d_out, int out_size, void* d_ws, size_t ws_size,
                              hipStream_t stream)
{
    const float* x  = (const float*)d_in[0];
    const float* w1 = (const float*)d_in[1];
    const float* b1 = (const float*)d_in[2];
    const float* w2 = (const float*)d_in[3];
    const float* b2 = (const float*)d_in[4];
    float* out = (float*)d_out;
    float* ws  = (float*)d_ws;     // ~23 MB used

    prep_kernel<<<2560, 256, 0, stream>>>(x, w1, ws);
    // 512 blocks, 2/CU (64 KB LDS each): 256 GEMM tiles + 256 zero slices overlap.
    fused_kernel<<<512, 256, 0, stream>>>(b1, w2, ws, out);
    router2_kernel<<<16, 256, 0, stream>>>(ws, b2, out);
    aux_kernel<<<1, 256, 0, stream>>>(out);
}